// Round 12
// baseline (248.411 us; speedup 1.0000x reference)
//
#include <hip/hip_runtime.h>

// Capsule dynamic routing — R7 body (b-on-lanes / o-on-waves, wave-uniform
// scalar w-loads, u global) + 2x block supply along n (runtime ws-guarded).
// u_i:(B,N,DI) f32, w:(1,N,NO,DI,DE) f32, bias:(N,NO,1) f32, r=3.
// Identity: logits_r = u_ji . vsum (vsum = running sum of v; u_ji includes
// bias so the bias term folds in automatically).
// Block = 5 waves x 64 lanes; wave wv owns o{2wv,2wv+1}; lane = b.
// Ranking so far (per pass): R7(u glob + w scalar)=44 < R10(u LDS)=49 <
// R11(w LDS)=54.6 — every data-path variant of R7 loses; the untried lever
// is block count (R7 = 2.25 blocks/CU, occupancy 14%). NTILE=4 doubles it;
// s_part grows to 47.2 MB -> chosen at runtime iff ws_size allows.

#define B    256
#define N    1152
#define NO   10
#define DI   8
#define DE   16
#define BG      64     // b per block (= lanes per wave)
#define BGS     4      // B / BG
#define THREADS 320    // 5 waves
#define SPSTRIDE (B * NO * DE)   // 40,960 floats per tile partial

// ---------------------------------------------------------------------------
// Routing pass. Grid: (N/NTILE_T n-tiles, 4 b-groups) x 320 threads.
// ---------------------------------------------------------------------------
template <int NTILE_T>
__global__ __launch_bounds__(THREADS, 3)
void routing_kernel(const float* __restrict__ u,
                    const float* __restrict__ w,
                    const float* __restrict__ bias,
                    const float* __restrict__ vsum,
                    float* __restrict__ s_part,
                    const int has_v) {
    __shared__ float lgx[2][NO][BG];               // 5 KB dbuf logit exchange
    const int tid  = threadIdx.x;
    const int lane = tid & 63;
    const int wv   = __builtin_amdgcn_readfirstlane(tid >> 6);  // 0..4 uniform
    const int o0   = wv * 2;
    const int b    = blockIdx.y * BG + lane;
    const int n0   = blockIdx.x * NTILE_T;

    // vsum fragment for this thread's (b, o0..o0+1), full e — loop-invariant
    float4 vv[2][4];
#pragma unroll
    for (int oi = 0; oi < 2; ++oi)
#pragma unroll
        for (int eq = 0; eq < 4; ++eq)
            vv[oi][eq] = make_float4(0.f, 0.f, 0.f, 0.f);
    if (has_v) {
#pragma unroll
        for (int oi = 0; oi < 2; ++oi)
#pragma unroll
            for (int eq = 0; eq < 4; ++eq)
                vv[oi][eq] = *(const float4*)(vsum + ((size_t)b * NO + o0 + oi) * DE + eq * 4);
    }

    float4 acc[2][4];
#pragma unroll
    for (int oi = 0; oi < 2; ++oi)
#pragma unroll
        for (int eq = 0; eq < 4; ++eq)
            acc[oi][eq] = make_float4(0.f, 0.f, 0.f, 0.f);

    for (int i = 0; i < NTILE_T; ++i) {
        const int n = n0 + i;

        // u row for this b (lanes scatter over b; 5 waves/block share lines)
        const float* up = u + ((size_t)b * N + n) * DI;
        const float4 u0 = *(const float4*)up;
        const float4 u1 = *(const float4*)(up + 4);
        const float ur[DI] = {u0.x, u0.y, u0.z, u0.w, u1.x, u1.y, u1.z, u1.w};

        // u_ji for (o0, o0+1), all 16 e — weight addrs wave-uniform -> s_load
        const float* wp = w + ((size_t)n * NO + o0) * (DI * DE);
        float4 uji[2][4];
#pragma unroll
        for (int oi = 0; oi < 2; ++oi) {
            const float bv = bias[n * NO + o0 + oi];
#pragma unroll
            for (int eq = 0; eq < 4; ++eq)
                uji[oi][eq] = make_float4(bv, bv, bv, bv);
#pragma unroll
            for (int d = 0; d < DI; ++d) {
                const float* wrow = wp + oi * (DI * DE) + d * DE;
#pragma unroll
                for (int eq = 0; eq < 4; ++eq) {
                    const float4 w4 = *(const float4*)(wrow + eq * 4);
                    uji[oi][eq].x += ur[d] * w4.x;
                    uji[oi][eq].y += ur[d] * w4.y;
                    uji[oi][eq].z += ur[d] * w4.z;
                    uji[oi][eq].w += ur[d] * w4.w;
                }
            }
        }

        float c[2];
        if (has_v) {
            // logits: full-e dot in-thread; exchange via double-buffered LDS
            const int buf = i & 1;
#pragma unroll
            for (int oi = 0; oi < 2; ++oi) {
                float lg = 0.f;
#pragma unroll
                for (int eq = 0; eq < 4; ++eq)
                    lg += uji[oi][eq].x * vv[oi][eq].x + uji[oi][eq].y * vv[oi][eq].y
                        + uji[oi][eq].z * vv[oi][eq].z + uji[oi][eq].w * vv[oi][eq].w;
                lgx[buf][o0 + oi][lane] = lg;
            }
            __syncthreads();   // single barrier/n; buffer parity protects reads
            float l[NO];
#pragma unroll
            for (int o = 0; o < NO; ++o) l[o] = lgx[buf][o][lane];

            float m = l[0];
#pragma unroll
            for (int o = 1; o < NO; ++o) m = fmaxf(m, l[o]);
            float sum = 0.f;
#pragma unroll
            for (int o = 0; o < NO; ++o) { l[o] = __expf(l[o] - m); sum += l[o]; }
            const float inv = 1.f / sum;
            c[0] = l[o0] * inv;
            c[1] = l[o0 + 1] * inv;
        } else {
            c[0] = 0.1f; c[1] = 0.1f;   // softmax of zeros
        }

#pragma unroll
        for (int oi = 0; oi < 2; ++oi)
#pragma unroll
            for (int eq = 0; eq < 4; ++eq) {
                acc[oi][eq].x += c[oi] * uji[oi][eq].x;
                acc[oi][eq].y += c[oi] * uji[oi][eq].y;
                acc[oi][eq].z += c[oi] * uji[oi][eq].z;
                acc[oi][eq].w += c[oi] * uji[oi][eq].w;
            }
    }

    // s_part[tile][b][o][e]
    float* sp = s_part + (((size_t)blockIdx.x * B + b) * NO + o0) * DE;
#pragma unroll
    for (int oi = 0; oi < 2; ++oi)
#pragma unroll
        for (int eq = 0; eq < 4; ++eq)
            *(float4*)(sp + oi * DE + eq * 4) = acc[oi][eq];
}

// ---------------------------------------------------------------------------
// Squash: s = sum_tiles s_part; v = ||s||/(1+||s||^2)*s; out = v; vsum += v.
// Grid 160 blocks x 256 thr; block owns 64 consecutive f4. Wave q sums tiles
// [q*tpw, (q+1)*tpw) with lanes = consecutive f4 (coalesced 1 KB/wave);
// 4-wave LDS combine; wave 0 does the norm (4 eq lanes per (b,o)) + writes.
// ---------------------------------------------------------------------------
__global__ __launch_bounds__(256)
void squash_kernel(const float* __restrict__ s_part,
                   float* __restrict__ vsum,
                   float* __restrict__ out,
                   const int tpw,          // tiles per wave = ntiles/4
                   const int accum) {
    __shared__ __align__(16) float4 part[4][64];
    const int tid  = threadIdx.x;
    const int lane = tid & 63;
    const int q    = tid >> 6;
    const int f4   = blockIdx.x * 64 + lane;   // global float4 index, <10240

    const float4* sp = (const float4*)s_part + (size_t)(q * tpw) * (SPSTRIDE / 4) + f4;
    float4 s = make_float4(0.f, 0.f, 0.f, 0.f);
    for (int i = 0; i < tpw; ++i) {
        const float4 t = sp[(size_t)i * (SPSTRIDE / 4)];
        s.x += t.x; s.y += t.y; s.z += t.z; s.w += t.w;
    }
    part[q][lane] = s;
    __syncthreads();

    if (q == 0) {
#pragma unroll
        for (int j = 1; j < 4; ++j) {
            const float4 t = part[j][lane];
            s.x += t.x; s.y += t.y; s.z += t.z; s.w += t.w;
        }
        float nsq = s.x * s.x + s.y * s.y + s.z * s.z + s.w * s.w;
        nsq += __shfl_xor(nsq, 1);
        nsq += __shfl_xor(nsq, 2);          // full ||s||^2 over the 4 eq lanes
        const float nrm   = sqrtf(nsq);
        const float scale = nrm / (1.f + nsq);
        const float4 val = make_float4(s.x * scale, s.y * scale,
                                       s.z * scale, s.w * scale);
        ((float4*)out)[f4] = val;
        float4* vp = (float4*)vsum + f4;
        if (accum) {
            const float4 old = *vp;
            *vp = make_float4(old.x + val.x, old.y + val.y,
                              old.z + val.z, old.w + val.w);
        } else {
            *vp = val;
        }
    }
}

extern "C" void kernel_launch(void* const* d_in, const int* in_sizes, int n_in,
                              void* d_out, int out_size, void* d_ws, size_t ws_size,
                              hipStream_t stream) {
    const float* u    = (const float*)d_in[0];
    const float* w    = (const float*)d_in[1];   // (N,NO,DI,DE)
    const float* bias = (const float*)d_in[2];   // (N,NO)
    // d_in[3] = r, static 3

    // Pick NTILE by workspace: 4 (288 tiles, 47.4 MB) if it fits, else 8.
    const size_t need4 = ((size_t)(N / 4) * SPSTRIDE + SPSTRIDE) * sizeof(float);
    const bool   big   = ws_size >= need4;
    const int    ntiles = big ? (N / 4) : (N / 8);

    float* wsf    = (float*)d_ws;
    float* s_part = wsf;
    float* vsum   = wsf + (size_t)ntiles * SPSTRIDE;
    float* out    = (float*)d_out;

    const dim3 rgrid(ntiles, BGS), rblk(THREADS);
    for (int it = 0; it < 3; ++it) {
        if (big)
            routing_kernel<4><<<rgrid, rblk, 0, stream>>>(u, w, bias, vsum, s_part, it > 0);
        else
            routing_kernel<8><<<rgrid, rblk, 0, stream>>>(u, w, bias, vsum, s_part, it > 0);
        squash_kernel<<<160, 256, 0, stream>>>(s_part, vsum, out, ntiles / 4, it > 0);
    }
}